// Round 3
// baseline (11477.416 us; speedup 1.0000x reference)
//
#include <hip/hip_runtime.h>
#include <hip/hip_bf16.h>

typedef __hip_bfloat16 bf16;
typedef __attribute__((ext_vector_type(8))) __bf16 bf16x8;
typedef __attribute__((ext_vector_type(4))) float f32x4;

#define DEVI __device__ __forceinline__

DEVI float sigm(float x) { return 1.f / (1.f + __expf(-x)); }
DEVI float tanh_fast(float x) { float e = __expf(2.f * x); return 1.f - 2.f / (e + 1.f); }
DEVI float us2f(unsigned short u) { return __uint_as_float(((unsigned)u) << 16); }

DEVI __bf16 f2b(float f) {               // RNE f32->bf16
    unsigned u = __float_as_uint(f);
    u = u + 0x7FFFu + ((u >> 16) & 1u);
    unsigned short s = (unsigned short)(u >> 16);
    __bf16 b;
    __builtin_memcpy(&b, &s, 2);
    return b;
}

DEVI f32x4 MFMA(bf16x8 a, bf16x8 b, f32x4 c) {
    return __builtin_amdgcn_mfma_f32_16x16x32_bf16(a, b, c, 0, 0, 0);
}

// load 8 consecutive elements as bf16x8, converting if source is f32
DEVI bf16x8 load8(const bf16* p) { return *reinterpret_cast<const bf16x8*>(p); }
DEVI bf16x8 load8(const float* p) {
    float4 a = *reinterpret_cast<const float4*>(p);
    float4 b = *reinterpret_cast<const float4*>(p + 4);
    bf16x8 r;
    r[0] = f2b(a.x); r[1] = f2b(a.y); r[2] = f2b(a.z); r[3] = f2b(a.w);
    r[4] = f2b(b.x); r[5] = f2b(b.y); r[6] = f2b(b.z); r[7] = f2b(b.w);
    return r;
}

// ---------------------------------------------------------------------------
// Generic MFMA GEMM:  C[m,n] = sum_k A[m,k] * B[n,k] + bias[n]
// A row-major [M][lda] (f32 or bf16; rows optionally gathered via Aidx),
// B row-major [N][ldb] (f32 or bf16) with column offset boff. 128x128 tile,
// BK=32, register-staged LDS with inline f32->bf16 conversion.
// Grid: (N/128, M/128). Stores guarded by row < M_real.
// ---------------------------------------------------------------------------
template<typename AT, typename BT, bool GATHER>
__global__ __launch_bounds__(256)
void gemm_bt(const AT* __restrict__ A, const int* __restrict__ Aidx, int lda,
             const BT* __restrict__ B, int ldb, int boff,
             const float* __restrict__ bias,
             float* __restrict__ C, long ldc,
             int M_real, int K)
{
    __shared__ __attribute__((aligned(16))) bf16 As[128 * 32];
    __shared__ __attribute__((aligned(16))) bf16 Bs[128 * 32];
    const int tid = threadIdx.x;
    const int lane = tid & 63;
    const int w = tid >> 6;
    const int wr = w >> 1, wc = w & 1;
    const int bm = blockIdx.y * 128;
    const int bn = blockIdx.x * 128;

    // staging: thread covers two 8-element chunks per matrix
    const int l16_0 = (2 * w + 0) * 64 + lane;   // 8-elem chunk index in tile
    const int l16_1 = (2 * w + 1) * 64 + lane;
    const int row0 = l16_0 >> 2, c0 = l16_0 & 3;
    const int row1 = l16_1 >> 2, c1 = l16_1 & 3;

    long arow0 = GATHER ? (long)Aidx[bm + row0] : (long)(bm + row0);
    long arow1 = GATHER ? (long)Aidx[bm + row1] : (long)(bm + row1);
    const AT* agp0 = A + arow0 * lda + c0 * 8;
    const AT* agp1 = A + arow1 * lda + c1 * 8;
    const BT* bgp0 = B + (long)(bn + row0) * ldb + boff + c0 * 8;
    const BT* bgp1 = B + (long)(bn + row1) * ldb + boff + c1 * 8;

    f32x4 acc[4][4];
    #pragma unroll
    for (int i = 0; i < 4; i++)
        #pragma unroll
        for (int j = 0; j < 4; j++) acc[i][j] = f32x4{0.f, 0.f, 0.f, 0.f};

    const bf16x8* Asv = reinterpret_cast<const bf16x8*>(As);
    const bf16x8* Bsv = reinterpret_cast<const bf16x8*>(Bs);
    bf16x8* AsW = reinterpret_cast<bf16x8*>(As);
    bf16x8* BsW = reinterpret_cast<bf16x8*>(Bs);
    const int kq = lane >> 4;      // 0..3
    const int lrow = lane & 15;

    // prefetch tile 0
    bf16x8 ra0 = load8(agp0);
    bf16x8 ra1 = load8(agp1);
    bf16x8 rb0 = load8(bgp0);
    bf16x8 rb1 = load8(bgp1);

    for (int k0 = 0; k0 < K; k0 += 32) {
        __syncthreads();                 // previous tile fully consumed
        AsW[l16_0] = ra0; AsW[l16_1] = ra1;
        BsW[l16_0] = rb0; BsW[l16_1] = rb1;
        __syncthreads();                 // tile ready

        const int kn = k0 + 32;
        if (kn < K) {                    // prefetch next tile (overlaps MFMA)
            ra0 = load8(agp0 + kn);
            ra1 = load8(agp1 + kn);
            rb0 = load8(bgp0 + kn);
            rb1 = load8(bgp1 + kn);
        }

        bf16x8 af[4], bfr[4];
        #pragma unroll
        for (int mt = 0; mt < 4; mt++) af[mt] = Asv[(wr * 64 + mt * 16 + lrow) * 4 + kq];
        #pragma unroll
        for (int nt = 0; nt < 4; nt++) bfr[nt] = Bsv[(wc * 64 + nt * 16 + lrow) * 4 + kq];
        #pragma unroll
        for (int mt = 0; mt < 4; mt++)
            #pragma unroll
            for (int nt = 0; nt < 4; nt++)
                acc[mt][nt] = MFMA(af[mt], bfr[nt], acc[mt][nt]);
    }

    const int rbase = kq * 4;
    #pragma unroll
    for (int nt = 0; nt < 4; nt++) {
        const int col = bn + wc * 64 + nt * 16 + lrow;
        const float bv = bias[col];
        #pragma unroll
        for (int mt = 0; mt < 4; mt++) {
            const int rw = bm + wr * 64 + mt * 16 + rbase;
            #pragma unroll
            for (int r = 0; r < 4; r++) {
                const int row = rw + r;
                if (row < M_real) C[(long)row * ldc + col] = acc[mt][nt][r] + bv;
            }
        }
    }
}

// ---------------------------------------------------------------------------
// f32 -> bf16 bulk convert (n multiple of 4)
// ---------------------------------------------------------------------------
__global__ __launch_bounds__(256)
void cvt_f32_bf16(const float* __restrict__ in, bf16* __restrict__ out, int n)
{
    int i = (blockIdx.x * blockDim.x + threadIdx.x) * 4;
    if (i < n) {
        float4 v = *reinterpret_cast<const float4*>(in + i);
        ushort4 o;
        __bf16 b0 = f2b(v.x), b1 = f2b(v.y), b2 = f2b(v.z), b3 = f2b(v.w);
        __builtin_memcpy(&o.x, &b0, 2); __builtin_memcpy(&o.y, &b1, 2);
        __builtin_memcpy(&o.z, &b2, 2); __builtin_memcpy(&o.w, &b3, 2);
        *reinterpret_cast<ushort4*>(out + i) = o;
    }
}

// ---------------------------------------------------------------------------
// pa[wg][b][e] = sum_{k in 16-col slice} h2[b,k] * attn_W[e, j0+k]   (Wh part)
// ---------------------------------------------------------------------------
DEVI void pa_from_h2(const float (*h2s)[16], const float* __restrict__ attnW,
                     float* __restrict__ pa, int j0, int wg, int lane)
{
    #pragma unroll
    for (int e8 = 0; e8 < 8; e8++) {
        const int e = e8 * 64 + lane;
        const float* wr_ = attnW + (size_t)e * 2048 + j0;
        float wcol[16];
        #pragma unroll
        for (int k = 0; k < 16; k++) wcol[k] = wr_[k];
        float* po = pa + (size_t)wg * 16384 + e;
        for (int b = 0; b < 32; b++) {
            float s = 0.f;
            #pragma unroll
            for (int k = 0; k < 16; k++) s += wcol[k] * h2s[b][k];
            po[b * 512] = s;
        }
    }
}

// ---------------------------------------------------------------------------
// Encoder GRU step. 64 blocks x 64 threads (1 wave). Block owns 16 H-columns.
// gh = h @ enc_Whh^T (+bhh); gi precomputed in X. Writes h_next (f32+bf16), enc.
// ---------------------------------------------------------------------------
__global__ __launch_bounds__(64)
void enc_step(const bf16* __restrict__ h_bf, const float* __restrict__ h_f,
              const float* __restrict__ X, int t,
              const bf16* __restrict__ Whh, const float* __restrict__ bhh,
              float* __restrict__ h_f_n, bf16* __restrict__ h_bf_n,
              bf16* __restrict__ enc_out,
              const float* __restrict__ attnW, float* __restrict__ pa, int do_pa)
{
    __shared__ float h2s[32][16];
    const int lane = threadIdx.x;
    const int j0 = blockIdx.x * 16;
    const int lrow = lane & 15;
    const int kq = lane >> 4;

    f32x4 acc[3][2];
    #pragma unroll
    for (int g = 0; g < 3; g++) { acc[g][0] = f32x4{0,0,0,0}; acc[g][1] = f32x4{0,0,0,0}; }

    const bf16x8* hv = reinterpret_cast<const bf16x8*>(h_bf);
    const bf16x8* wv = reinterpret_cast<const bf16x8*>(Whh);
    const int a0r = lrow * 128 + kq;
    const int a1r = (16 + lrow) * 128 + kq;
    const int b0r = (j0 + lrow) * 128 + kq;
    const int b1r = (1024 + j0 + lrow) * 128 + kq;
    const int b2r = (2048 + j0 + lrow) * 128 + kq;

    #pragma unroll 4
    for (int kv = 0; kv < 128; kv += 4) {
        bf16x8 a0 = hv[a0r + kv];
        bf16x8 a1 = hv[a1r + kv];
        bf16x8 b0 = wv[b0r + kv];
        bf16x8 b1 = wv[b1r + kv];
        bf16x8 b2 = wv[b2r + kv];
        acc[0][0] = MFMA(a0, b0, acc[0][0]); acc[0][1] = MFMA(a1, b0, acc[0][1]);
        acc[1][0] = MFMA(a0, b1, acc[1][0]); acc[1][1] = MFMA(a1, b1, acc[1][1]);
        acc[2][0] = MFMA(a0, b2, acc[2][0]); acc[2][1] = MFMA(a1, b2, acc[2][1]);
    }

    const int j = j0 + lrow;
    const float bhr = bhh[j];
    const float bhz = bhh[1024 + j];
    const float bhn = bhh[2048 + j];

    #pragma unroll
    for (int mt = 0; mt < 2; mt++) {
        #pragma unroll
        for (int r = 0; r < 4; r++) {
            const int b = mt * 16 + kq * 4 + r;
            const size_t xi = ((size_t)b * 64 + t) * 3072 + j;
            float gir = X[xi], giz = X[xi + 1024], gin = X[xi + 2048];
            float rr = sigm(gir + acc[0][mt][r] + bhr);
            float zz = sigm(giz + acc[1][mt][r] + bhz);
            float nn = tanh_fast(gin + rr * (acc[2][mt][r] + bhn));
            float ho = h_f[b * 1024 + j];
            float h2 = (1.f - zz) * nn + zz * ho;
            h_f_n[b * 1024 + j] = h2;
            bf16 hb = __float2bfloat16(h2);
            h_bf_n[b * 1024 + j] = hb;
            enc_out[((size_t)b * 64 + t) * 1024 + j] = hb;
            h2s[b][lrow] = h2;
        }
    }
    if (do_pa) {
        __syncthreads();
        pa_from_h2(h2s, attnW, pa, j0, blockIdx.x, lane);
    }
}

// ---------------------------------------------------------------------------
// Decoder GRU step: gi = X_dec(emb part) + ctx @ dec_Wih[:,512:]^T,
// gh = h @ dec_Whh^T (+bhh). Also emits pa for next step's attention.
// ---------------------------------------------------------------------------
__global__ __launch_bounds__(64)
void dec_step(const bf16* __restrict__ h_bf, const float* __restrict__ h_f,
              const bf16* __restrict__ ctx_bf,
              const float* __restrict__ X, int t,
              const bf16* __restrict__ Whh, const float* __restrict__ bhh,
              const bf16* __restrict__ Wih,
              float* __restrict__ h_f_n, bf16* __restrict__ h_bf_n,
              bf16* __restrict__ Hall,
              const float* __restrict__ attnW, float* __restrict__ pa, int do_pa)
{
    __shared__ float h2s[32][16];
    const int lane = threadIdx.x;
    const int j0 = blockIdx.x * 16;
    const int lrow = lane & 15;
    const int kq = lane >> 4;

    f32x4 acch[3][2], accc[3][2];
    #pragma unroll
    for (int g = 0; g < 3; g++) {
        acch[g][0] = f32x4{0,0,0,0}; acch[g][1] = f32x4{0,0,0,0};
        accc[g][0] = f32x4{0,0,0,0}; accc[g][1] = f32x4{0,0,0,0};
    }

    const bf16x8* hv = reinterpret_cast<const bf16x8*>(h_bf);
    const bf16x8* cv = reinterpret_cast<const bf16x8*>(ctx_bf);
    const bf16x8* wv = reinterpret_cast<const bf16x8*>(Whh);
    const bf16x8* uv = reinterpret_cast<const bf16x8*>(Wih);
    const int hr0 = lrow * 128 + kq, hr1 = (16 + lrow) * 128 + kq;
    const int wb0 = (j0 + lrow) * 128 + kq;
    const int wb1 = (1024 + j0 + lrow) * 128 + kq;
    const int wb2 = (2048 + j0 + lrow) * 128 + kq;
    const int ub0 = (j0 + lrow) * 192 + 64 + kq;          // ldb=1536 -> 192 v8, +512 col -> +64 v8
    const int ub1 = (1024 + j0 + lrow) * 192 + 64 + kq;
    const int ub2 = (2048 + j0 + lrow) * 192 + 64 + kq;

    #pragma unroll 2
    for (int kv = 0; kv < 128; kv += 4) {
        bf16x8 ah0 = hv[hr0 + kv], ah1 = hv[hr1 + kv];
        bf16x8 ac0 = cv[hr0 + kv], ac1 = cv[hr1 + kv];
        bf16x8 b0 = wv[wb0 + kv], b1 = wv[wb1 + kv], b2 = wv[wb2 + kv];
        bf16x8 u0 = uv[ub0 + kv], u1 = uv[ub1 + kv], u2 = uv[ub2 + kv];
        acch[0][0] = MFMA(ah0, b0, acch[0][0]); acch[0][1] = MFMA(ah1, b0, acch[0][1]);
        acch[1][0] = MFMA(ah0, b1, acch[1][0]); acch[1][1] = MFMA(ah1, b1, acch[1][1]);
        acch[2][0] = MFMA(ah0, b2, acch[2][0]); acch[2][1] = MFMA(ah1, b2, acch[2][1]);
        accc[0][0] = MFMA(ac0, u0, accc[0][0]); accc[0][1] = MFMA(ac1, u0, accc[0][1]);
        accc[1][0] = MFMA(ac0, u1, accc[1][0]); accc[1][1] = MFMA(ac1, u1, accc[1][1]);
        accc[2][0] = MFMA(ac0, u2, accc[2][0]); accc[2][1] = MFMA(ac1, u2, accc[2][1]);
    }

    const int j = j0 + lrow;
    const float bhr = bhh[j];
    const float bhz = bhh[1024 + j];
    const float bhn = bhh[2048 + j];

    #pragma unroll
    for (int mt = 0; mt < 2; mt++) {
        #pragma unroll
        for (int r = 0; r < 4; r++) {
            const int b = mt * 16 + kq * 4 + r;
            const size_t xi = ((size_t)b * 63 + t) * 3072 + j;
            float gir = X[xi] + accc[0][mt][r];
            float giz = X[xi + 1024] + accc[1][mt][r];
            float gin = X[xi + 2048] + accc[2][mt][r];
            float rr = sigm(gir + acch[0][mt][r] + bhr);
            float zz = sigm(giz + acch[1][mt][r] + bhz);
            float nn = tanh_fast(gin + rr * (acch[2][mt][r] + bhn));
            float ho = h_f[b * 1024 + j];
            float h2 = (1.f - zz) * nn + zz * ho;
            h_f_n[b * 1024 + j] = h2;
            bf16 hb = __float2bfloat16(h2);
            h_bf_n[b * 1024 + j] = hb;
            Hall[((size_t)b * 63 + t) * 1024 + j] = hb;
            h2s[b][lrow] = h2;
        }
    }
    if (do_pa) {
        __syncthreads();
        pa_from_h2(h2s, attnW, pa, j0, blockIdx.x, lane);
    }
}

// ---------------------------------------------------------------------------
// Attention: reduce pa -> a[b,:]; scores = v.tanh(enc_proj + a); softmax; ctx.
// 32 blocks (one per batch) x 256 threads.
// ---------------------------------------------------------------------------
__global__ __launch_bounds__(256)
void attn_step(const float* __restrict__ pa, const float* __restrict__ enc_pj,
               const bf16* __restrict__ enc, const float* __restrict__ v_w,
               bf16* __restrict__ ctx)
{
    __shared__ float a_s[512];
    __shared__ float vw_s[512];
    __shared__ float sc[64];
    __shared__ float wsm[64];
    const int b = blockIdx.x, tid = threadIdx.x;

    vw_s[tid] = v_w[tid];
    vw_s[256 + tid] = v_w[256 + tid];

    float sx = 0.f, sy = 0.f;
    const float* pb = pa + b * 512 + tid * 2;
    #pragma unroll 8
    for (int w = 0; w < 64; w++) {
        float2 v = *reinterpret_cast<const float2*>(pb + (size_t)w * 16384);
        sx += v.x; sy += v.y;
    }
    a_s[2 * tid] = sx; a_s[2 * tid + 1] = sy;
    __syncthreads();

    const int sI = tid >> 2, q = tid & 3;
    const float* ep = enc_pj + ((size_t)b * 64 + sI) * 512 + q * 128;
    float part = 0.f;
    for (int e = 0; e < 128; e++) {
        float x = ep[e] + a_s[q * 128 + e];
        part += vw_s[q * 128 + e] * tanh_fast(x);
    }
    part += __shfl_xor(part, 1);
    part += __shfl_xor(part, 2);
    if (q == 0) sc[sI] = part;
    __syncthreads();

    if (tid < 64) {
        float v = sc[tid];
        float m = v;
        #pragma unroll
        for (int off = 32; off; off >>= 1) m = fmaxf(m, __shfl_xor(m, off));
        float e = __expf(v - m);
        float su = e;
        #pragma unroll
        for (int off = 32; off; off >>= 1) su += __shfl_xor(su, off);
        wsm[tid] = e / su;
    }
    __syncthreads();

    float c0 = 0, c1 = 0, c2 = 0, c3 = 0;
    const bf16* eb = enc + (size_t)b * 65536 + tid * 4;
    for (int s = 0; s < 64; s++) {
        float w = wsm[s];
        ushort4 u = *reinterpret_cast<const ushort4*>(eb + s * 1024);
        c0 += w * us2f(u.x); c1 += w * us2f(u.y);
        c2 += w * us2f(u.z); c3 += w * us2f(u.w);
    }
    ushort4 o;
    bf16 t0 = __float2bfloat16(c0), t1 = __float2bfloat16(c1);
    bf16 t2 = __float2bfloat16(c2), t3 = __float2bfloat16(c3);
    o.x = *(unsigned short*)&t0; o.y = *(unsigned short*)&t1;
    o.z = *(unsigned short*)&t2; o.w = *(unsigned short*)&t3;
    *reinterpret_cast<ushort4*>(ctx + b * 1024 + tid * 4) = o;
}

// ---------------------------------------------------------------------------
__global__ void init_k(float* __restrict__ h_f, bf16* __restrict__ h_bf,
                       bf16* __restrict__ hall_pad, int* __restrict__ idx_dec,
                       const int* __restrict__ tgt)
{
    const int i = blockIdx.x * blockDim.x + threadIdx.x;
    if (i < 32768) {
        h_f[i] = 0.f;
        h_bf[i] = __float2bfloat16(0.f);
        hall_pad[i] = __float2bfloat16(0.f);
    }
    if (i < 2048) {
        int v = 0;
        if (i < 2016) { int bb = i / 63; int tq = i - bb * 63; v = tgt[bb * 64 + tq]; }
        idx_dec[i] = v;
    }
}

// ---------------------------------------------------------------------------
extern "C" void kernel_launch(void* const* d_in, const int* in_sizes, int n_in,
                              void* d_out, int out_size, void* d_ws, size_t ws_size,
                              hipStream_t stream)
{
    const int*   src       = (const int*)d_in[0];
    const int*   tgt       = (const int*)d_in[1];
    const float* src_embed = (const float*)d_in[2];
    const float* tgt_embed = (const float*)d_in[3];
    const float* enc_Wih   = (const float*)d_in[4];
    const float* enc_Whh   = (const float*)d_in[5];
    const float* enc_bih   = (const float*)d_in[6];
    const float* enc_bhh   = (const float*)d_in[7];
    const float* dec_Wih   = (const float*)d_in[8];
    const float* dec_Whh   = (const float*)d_in[9];
    const float* dec_bih   = (const float*)d_in[10];
    const float* dec_bhh   = (const float*)d_in[11];
    const float* attn_W    = (const float*)d_in[12];
    const float* attn_b    = (const float*)d_in[13];
    const float* v_w       = (const float*)d_in[14];
    const float* fc_W      = (const float*)d_in[15];
    const float* fc_b      = (const float*)d_in[16];

    char* w = (char*)d_ws;
    float* X_enc      = (float*)(w);                 // [2048][3072] f32
    float* X_dec      = (float*)(w + 25165824);      // [2048][3072] f32
    bf16*  enc_bf     = (bf16*) (w + 50331648);      // [32][64][1024] bf16
    float* enc_pj     = (float*)(w + 54525952);      // [2048][512] f32
    bf16*  H_all      = (bf16*) (w + 58720256);      // [2048][1024] bf16
    float* h_f        = (float*)(w + 62914560);      // 2 x [32][1024] f32
    bf16*  h_bf       = (bf16*) (w + 63176704);      // 2 x [32][1024] bf16
    bf16*  ctx_bf     = (bf16*) (w + 63307776);      // [32][1024] bf16
    float* pa         = (float*)(w + 63373312);      // [64][32][512] f32
    int*   idx_dec    = (int*)  (w + 67567616);      // [2048]
    bf16*  enc_Whh_bf = (bf16*) (w + 67575808);      // [3072][1024] bf16
    bf16*  dec_Whh_bf = (bf16*) (w + 73867264);      // [3072][1024] bf16
    bf16*  dec_Wih_bf = (bf16*) (w + 80158720);      // [3072][1536] bf16
    // total: 89,595,904 bytes

    init_k<<<128, 256, 0, stream>>>(h_f, h_bf, H_all + 2016 * 1024, idx_dec, tgt);
    cvt_f32_bf16<<<3072, 256, 0, stream>>>(enc_Whh, enc_Whh_bf, 3145728);
    cvt_f32_bf16<<<3072, 256, 0, stream>>>(dec_Whh, dec_Whh_bf, 3145728);
    cvt_f32_bf16<<<4608, 256, 0, stream>>>(dec_Wih, dec_Wih_bf, 4718592);

    // X_enc = gather(src_embed, src) @ enc_Wih^T + enc_bih
    gemm_bt<float, float, true><<<dim3(24, 16), 256, 0, stream>>>(
        src_embed, src, 512, enc_Wih, 512, 0, enc_bih, X_enc, 3072, 2048, 512);
    // X_dec = gather(tgt_embed, tgt[:, :-1]) @ dec_Wih[:, :512]^T + dec_bih
    gemm_bt<float, float, true><<<dim3(24, 16), 256, 0, stream>>>(
        tgt_embed, idx_dec, 512, dec_Wih, 1536, 0, dec_bih, X_dec, 3072, 2048, 512);

    for (int t = 0; t < 64; t++) {
        int cur = t & 1, nxt = cur ^ 1;
        enc_step<<<64, 64, 0, stream>>>(h_bf + cur * 32768, h_f + cur * 32768, X_enc, t,
                                        enc_Whh_bf, enc_bhh,
                                        h_f + nxt * 32768, h_bf + nxt * 32768, enc_bf,
                                        attn_W, pa, (t == 63) ? 1 : 0);
    }

    // enc_proj = enc @ We^T + attn_b   (We = attn_W[:, 1024:])
    gemm_bt<bf16, float, false><<<dim3(4, 16), 256, 0, stream>>>(
        enc_bf, nullptr, 1024, attn_W, 2048, 1024, attn_b, enc_pj, 512, 2048, 1024);

    for (int t = 0; t < 63; t++) {
        int cur = t & 1, nxt = cur ^ 1;
        attn_step<<<32, 256, 0, stream>>>(pa, enc_pj, enc_bf, v_w, ctx_bf);
        dec_step<<<64, 64, 0, stream>>>(h_bf + cur * 32768, h_f + cur * 32768, ctx_bf,
                                        X_dec, t, dec_Whh_bf, dec_bhh, dec_Wih_bf,
                                        h_f + nxt * 32768, h_bf + nxt * 32768, H_all,
                                        attn_W, pa, (t < 62) ? 1 : 0);
    }

    // logits = H_all @ fc_W^T + fc_b  -> d_out (f32), rows m = b*63+t
    gemm_bt<bf16, float, false><<<dim3(250, 16), 256, 0, stream>>>(
        H_all, nullptr, 1024, fc_W, 1024, 0, fc_b, (float*)d_out, 32000, 2016, 1024);
}

// Round 4
// 2979.116 us; speedup vs baseline: 3.8526x; 3.8526x over previous
//
#include <hip/hip_runtime.h>
#include <hip/hip_bf16.h>

typedef __hip_bfloat16 bf16;
typedef __attribute__((ext_vector_type(8))) __bf16 bf16x8;
typedef __attribute__((ext_vector_type(4))) float f32x4;

#define DEVI __device__ __forceinline__

DEVI float sigm(float x) { return 1.f / (1.f + __expf(-x)); }
DEVI float tanh_fast(float x) { float e = __expf(2.f * x); return 1.f - 2.f / (e + 1.f); }
DEVI float us2f(unsigned short u) { return __uint_as_float(((unsigned)u) << 16); }

DEVI __bf16 f2b(float f) {               // RNE f32->bf16
    unsigned u = __float_as_uint(f);
    u = u + 0x7FFFu + ((u >> 16) & 1u);
    unsigned short s = (unsigned short)(u >> 16);
    __bf16 b;
    __builtin_memcpy(&b, &s, 2);
    return b;
}

DEVI f32x4 MFMA(bf16x8 a, bf16x8 b, f32x4 c) {
    return __builtin_amdgcn_mfma_f32_16x16x32_bf16(a, b, c, 0, 0, 0);
}

// load 8 consecutive elements as bf16x8, converting if source is f32
DEVI bf16x8 load8(const bf16* p) { return *reinterpret_cast<const bf16x8*>(p); }
DEVI bf16x8 load8(const float* p) {
    float4 a = *reinterpret_cast<const float4*>(p);
    float4 b = *reinterpret_cast<const float4*>(p + 4);
    bf16x8 r;
    r[0] = f2b(a.x); r[1] = f2b(a.y); r[2] = f2b(a.z); r[3] = f2b(a.w);
    r[4] = f2b(b.x); r[5] = f2b(b.y); r[6] = f2b(b.z); r[7] = f2b(b.w);
    return r;
}

// ---------------------------------------------------------------------------
// Generic MFMA GEMM:  C[m,n] = sum_k A[m,k] * B[n,k] + bias[n]
// A row-major [M][lda] (f32 or bf16; rows optionally gathered via Aidx),
// B row-major [N][ldb] (f32 or bf16) with column offset boff. 128x128 tile,
// BK=32, register-staged LDS with inline f32->bf16 conversion.
// SWAP=false: grid (N/128, M/128);  SWAP=true: grid (M/128, N/128) — puts the
// M-tiles x-fastest so all consumers of one B-panel are co-resident (L2 reuse).
// ---------------------------------------------------------------------------
template<typename AT, typename BT, bool GATHER, bool SWAP>
__global__ __launch_bounds__(256)
void gemm_bt(const AT* __restrict__ A, const int* __restrict__ Aidx, int lda,
             const BT* __restrict__ B, int ldb, int boff,
             const float* __restrict__ bias,
             float* __restrict__ C, long ldc,
             int M_real, int K)
{
    __shared__ __attribute__((aligned(16))) bf16 As[128 * 32];
    __shared__ __attribute__((aligned(16))) bf16 Bs[128 * 32];
    const int tid = threadIdx.x;
    const int lane = tid & 63;
    const int w = tid >> 6;
    const int wr = w >> 1, wc = w & 1;
    const int bm = (SWAP ? blockIdx.x : blockIdx.y) * 128;
    const int bn = (SWAP ? blockIdx.y : blockIdx.x) * 128;

    // staging: thread covers two 8-element chunks per matrix
    const int l16_0 = (2 * w + 0) * 64 + lane;   // 8-elem chunk index in tile
    const int l16_1 = (2 * w + 1) * 64 + lane;
    const int row0 = l16_0 >> 2, c0 = l16_0 & 3;
    const int row1 = l16_1 >> 2, c1 = l16_1 & 3;

    long arow0 = GATHER ? (long)Aidx[bm + row0] : (long)(bm + row0);
    long arow1 = GATHER ? (long)Aidx[bm + row1] : (long)(bm + row1);
    const AT* agp0 = A + arow0 * lda + c0 * 8;
    const AT* agp1 = A + arow1 * lda + c1 * 8;
    const BT* bgp0 = B + (long)(bn + row0) * ldb + boff + c0 * 8;
    const BT* bgp1 = B + (long)(bn + row1) * ldb + boff + c1 * 8;

    f32x4 acc[4][4];
    #pragma unroll
    for (int i = 0; i < 4; i++)
        #pragma unroll
        for (int j = 0; j < 4; j++) acc[i][j] = f32x4{0.f, 0.f, 0.f, 0.f};

    const bf16x8* Asv = reinterpret_cast<const bf16x8*>(As);
    const bf16x8* Bsv = reinterpret_cast<const bf16x8*>(Bs);
    bf16x8* AsW = reinterpret_cast<bf16x8*>(As);
    bf16x8* BsW = reinterpret_cast<bf16x8*>(Bs);
    const int kq = lane >> 4;      // 0..3
    const int lrow = lane & 15;

    // prefetch tile 0
    bf16x8 ra0 = load8(agp0);
    bf16x8 ra1 = load8(agp1);
    bf16x8 rb0 = load8(bgp0);
    bf16x8 rb1 = load8(bgp1);

    for (int k0 = 0; k0 < K; k0 += 32) {
        __syncthreads();                 // previous tile fully consumed
        AsW[l16_0] = ra0; AsW[l16_1] = ra1;
        BsW[l16_0] = rb0; BsW[l16_1] = rb1;
        __syncthreads();                 // tile ready

        const int kn = k0 + 32;
        if (kn < K) {                    // prefetch next tile (overlaps MFMA)
            ra0 = load8(agp0 + kn);
            ra1 = load8(agp1 + kn);
            rb0 = load8(bgp0 + kn);
            rb1 = load8(bgp1 + kn);
        }

        bf16x8 af[4], bfr[4];
        #pragma unroll
        for (int mt = 0; mt < 4; mt++) af[mt] = Asv[(wr * 64 + mt * 16 + lrow) * 4 + kq];
        #pragma unroll
        for (int nt = 0; nt < 4; nt++) bfr[nt] = Bsv[(wc * 64 + nt * 16 + lrow) * 4 + kq];
        #pragma unroll
        for (int mt = 0; mt < 4; mt++)
            #pragma unroll
            for (int nt = 0; nt < 4; nt++)
                acc[mt][nt] = MFMA(af[mt], bfr[nt], acc[mt][nt]);
    }

    const int rbase = kq * 4;
    #pragma unroll
    for (int nt = 0; nt < 4; nt++) {
        const int col = bn + wc * 64 + nt * 16 + lrow;
        const float bv = bias[col];
        #pragma unroll
        for (int mt = 0; mt < 4; mt++) {
            const int rw = bm + wr * 64 + mt * 16 + rbase;
            #pragma unroll
            for (int r = 0; r < 4; r++) {
                const int row = rw + r;
                if (row < M_real) C[(long)row * ldc + col] = acc[mt][nt][r] + bv;
            }
        }
    }
}

// ---------------------------------------------------------------------------
// f32 -> bf16 bulk convert (n multiple of 4)
// ---------------------------------------------------------------------------
__global__ __launch_bounds__(256)
void cvt_f32_bf16(const float* __restrict__ in, bf16* __restrict__ out, int n)
{
    int i = (blockIdx.x * blockDim.x + threadIdx.x) * 4;
    if (i < n) {
        float4 v = *reinterpret_cast<const float4*>(in + i);
        ushort4 o;
        __bf16 b0 = f2b(v.x), b1 = f2b(v.y), b2 = f2b(v.z), b3 = f2b(v.w);
        __builtin_memcpy(&o.x, &b0, 2); __builtin_memcpy(&o.y, &b1, 2);
        __builtin_memcpy(&o.z, &b2, 2); __builtin_memcpy(&o.w, &b3, 2);
        *reinterpret_cast<ushort4*>(out + i) = o;
    }
}

// ---------------------------------------------------------------------------
// Encoder GRU step. 64 blocks x 512 threads (8 waves). Block owns 16 H-cols;
// wave kw owns K-slice [kw*128, kw*128+128). Partials reduced via LDS, then
// thread=(b,j) does the GRU pointwise. pa phase uses e=tid (512 e's).
// ---------------------------------------------------------------------------
__global__ __launch_bounds__(512)
void enc_step(const bf16* __restrict__ h_bf, const float* __restrict__ h_f,
              const float* __restrict__ X, int t,
              const bf16* __restrict__ Whh, const float* __restrict__ bhh,
              float* __restrict__ h_f_n, bf16* __restrict__ h_bf_n,
              bf16* __restrict__ enc_out,
              const float* __restrict__ attnW, float* __restrict__ pa, int do_pa)
{
    __shared__ float part[8][3][32][16];    // 48 KB
    __shared__ float h2s[32][16];
    const int tid = threadIdx.x;
    const int lane = tid & 63;
    const int kw = tid >> 6;                // K-slice wave 0..7
    const int j0 = blockIdx.x * 16;
    const int lrow = lane & 15;
    const int kq = lane >> 4;

    f32x4 acc[3][2];
    #pragma unroll
    for (int g = 0; g < 3; g++) { acc[g][0] = f32x4{0,0,0,0}; acc[g][1] = f32x4{0,0,0,0}; }

    const bf16x8* hv = reinterpret_cast<const bf16x8*>(h_bf);
    const bf16x8* wv = reinterpret_cast<const bf16x8*>(Whh);
    const int kb = kw * 16 + kq;            // v8 index base within the row
    const int a0r = lrow * 128 + kb;
    const int a1r = (16 + lrow) * 128 + kb;
    const int b0r = (j0 + lrow) * 128 + kb;
    const int b1r = (1024 + j0 + lrow) * 128 + kb;
    const int b2r = (2048 + j0 + lrow) * 128 + kb;

    #pragma unroll
    for (int kk = 0; kk < 4; kk++) {
        const int o = kk * 4;
        bf16x8 a0 = hv[a0r + o];
        bf16x8 a1 = hv[a1r + o];
        bf16x8 b0 = wv[b0r + o];
        bf16x8 b1 = wv[b1r + o];
        bf16x8 b2 = wv[b2r + o];
        acc[0][0] = MFMA(a0, b0, acc[0][0]); acc[0][1] = MFMA(a1, b0, acc[0][1]);
        acc[1][0] = MFMA(a0, b1, acc[1][0]); acc[1][1] = MFMA(a1, b1, acc[1][1]);
        acc[2][0] = MFMA(a0, b2, acc[2][0]); acc[2][1] = MFMA(a1, b2, acc[2][1]);
    }

    #pragma unroll
    for (int g = 0; g < 3; g++)
        #pragma unroll
        for (int mt = 0; mt < 2; mt++)
            #pragma unroll
            for (int r = 0; r < 4; r++)
                part[kw][g][mt * 16 + kq * 4 + r][lrow] = acc[g][mt][r];
    __syncthreads();

    const int b = tid >> 4, jc = tid & 15;
    const int j = j0 + jc;
    float s0 = 0.f, s1 = 0.f, s2 = 0.f;
    #pragma unroll
    for (int ww = 0; ww < 8; ww++) {
        s0 += part[ww][0][b][jc];
        s1 += part[ww][1][b][jc];
        s2 += part[ww][2][b][jc];
    }
    const size_t xi = ((size_t)b * 64 + t) * 3072 + j;
    float rr = sigm(X[xi] + s0 + bhh[j]);
    float zz = sigm(X[xi + 1024] + s1 + bhh[1024 + j]);
    float nn = tanh_fast(X[xi + 2048] + rr * (s2 + bhh[2048 + j]));
    float h2 = (1.f - zz) * nn + zz * h_f[b * 1024 + j];
    h_f_n[b * 1024 + j] = h2;
    bf16 hb = __float2bfloat16(h2);
    h_bf_n[b * 1024 + j] = hb;
    enc_out[((size_t)b * 64 + t) * 1024 + j] = hb;

    if (do_pa) {
        h2s[b][jc] = h2;
        __syncthreads();
        const int e = tid;                          // 512 e's, one per thread
        const float* wr_ = attnW + (size_t)e * 2048 + j0;
        float wcol[16];
        #pragma unroll
        for (int k = 0; k < 16; k++) wcol[k] = wr_[k];
        float* po = pa + (size_t)blockIdx.x * 16384 + e;
        for (int bb = 0; bb < 32; bb++) {
            float s = 0.f;
            #pragma unroll
            for (int k = 0; k < 16; k++) s += wcol[k] * h2s[bb][k];
            po[bb * 512] = s;
        }
    }
}

// ---------------------------------------------------------------------------
// Decoder GRU step: gi = X_dec(emb part) + ctx @ dec_Wih[:,512:]^T,
// gh = h @ dec_Whh^T (+bhh). 64 blocks x 512 threads, K-split as enc_step.
// ---------------------------------------------------------------------------
__global__ __launch_bounds__(512)
void dec_step(const bf16* __restrict__ h_bf, const float* __restrict__ h_f,
              const bf16* __restrict__ ctx_bf,
              const float* __restrict__ X, int t,
              const bf16* __restrict__ Whh, const float* __restrict__ bhh,
              const bf16* __restrict__ Wih,
              float* __restrict__ h_f_n, bf16* __restrict__ h_bf_n,
              bf16* __restrict__ Hall,
              const float* __restrict__ attnW, float* __restrict__ pa, int do_pa)
{
    __shared__ float part[8][6][32][16];    // 96 KB
    __shared__ float h2s[32][16];
    const int tid = threadIdx.x;
    const int lane = tid & 63;
    const int kw = tid >> 6;
    const int j0 = blockIdx.x * 16;
    const int lrow = lane & 15;
    const int kq = lane >> 4;

    f32x4 acc[6][2];
    #pragma unroll
    for (int g = 0; g < 6; g++) { acc[g][0] = f32x4{0,0,0,0}; acc[g][1] = f32x4{0,0,0,0}; }

    const bf16x8* hv = reinterpret_cast<const bf16x8*>(h_bf);
    const bf16x8* cv = reinterpret_cast<const bf16x8*>(ctx_bf);
    const bf16x8* wv = reinterpret_cast<const bf16x8*>(Whh);
    const bf16x8* uv = reinterpret_cast<const bf16x8*>(Wih);
    const int kb = kw * 16 + kq;
    const int hr0 = lrow * 128 + kb, hr1 = (16 + lrow) * 128 + kb;
    const int wb0 = (j0 + lrow) * 128 + kb;
    const int wb1 = (1024 + j0 + lrow) * 128 + kb;
    const int wb2 = (2048 + j0 + lrow) * 128 + kb;
    const int ub0 = (j0 + lrow) * 192 + 64 + kb;          // ldb=1536 -> 192 v8, +512 col -> +64 v8
    const int ub1 = (1024 + j0 + lrow) * 192 + 64 + kb;
    const int ub2 = (2048 + j0 + lrow) * 192 + 64 + kb;

    #pragma unroll
    for (int kk = 0; kk < 4; kk++) {
        const int o = kk * 4;
        bf16x8 ah0 = hv[hr0 + o], ah1 = hv[hr1 + o];
        bf16x8 ac0 = cv[hr0 + o], ac1 = cv[hr1 + o];
        bf16x8 b0 = wv[wb0 + o], b1 = wv[wb1 + o], b2 = wv[wb2 + o];
        bf16x8 u0 = uv[ub0 + o], u1 = uv[ub1 + o], u2 = uv[ub2 + o];
        acc[0][0] = MFMA(ah0, b0, acc[0][0]); acc[0][1] = MFMA(ah1, b0, acc[0][1]);
        acc[1][0] = MFMA(ah0, b1, acc[1][0]); acc[1][1] = MFMA(ah1, b1, acc[1][1]);
        acc[2][0] = MFMA(ah0, b2, acc[2][0]); acc[2][1] = MFMA(ah1, b2, acc[2][1]);
        acc[3][0] = MFMA(ac0, u0, acc[3][0]); acc[3][1] = MFMA(ac1, u0, acc[3][1]);
        acc[4][0] = MFMA(ac0, u1, acc[4][0]); acc[4][1] = MFMA(ac1, u1, acc[4][1]);
        acc[5][0] = MFMA(ac0, u2, acc[5][0]); acc[5][1] = MFMA(ac1, u2, acc[5][1]);
    }

    #pragma unroll
    for (int g = 0; g < 6; g++)
        #pragma unroll
        for (int mt = 0; mt < 2; mt++)
            #pragma unroll
            for (int r = 0; r < 4; r++)
                part[kw][g][mt * 16 + kq * 4 + r][lrow] = acc[g][mt][r];
    __syncthreads();

    const int b = tid >> 4, jc = tid & 15;
    const int j = j0 + jc;
    float h0 = 0.f, h1 = 0.f, h2g = 0.f, c0 = 0.f, c1 = 0.f, c2 = 0.f;
    #pragma unroll
    for (int ww = 0; ww < 8; ww++) {
        h0  += part[ww][0][b][jc];
        h1  += part[ww][1][b][jc];
        h2g += part[ww][2][b][jc];
        c0  += part[ww][3][b][jc];
        c1  += part[ww][4][b][jc];
        c2  += part[ww][5][b][jc];
    }
    const size_t xi = ((size_t)b * 63 + t) * 3072 + j;
    float rr = sigm(X[xi] + c0 + h0 + bhh[j]);
    float zz = sigm(X[xi + 1024] + c1 + h1 + bhh[1024 + j]);
    float nn = tanh_fast(X[xi + 2048] + c2 + rr * (h2g + bhh[2048 + j]));
    float h2 = (1.f - zz) * nn + zz * h_f[b * 1024 + j];
    h_f_n[b * 1024 + j] = h2;
    bf16 hb = __float2bfloat16(h2);
    h_bf_n[b * 1024 + j] = hb;
    Hall[((size_t)b * 63 + t) * 1024 + j] = hb;

    if (do_pa) {
        h2s[b][jc] = h2;
        __syncthreads();
        const int e = tid;
        const float* wr_ = attnW + (size_t)e * 2048 + j0;
        float wcol[16];
        #pragma unroll
        for (int k = 0; k < 16; k++) wcol[k] = wr_[k];
        float* po = pa + (size_t)blockIdx.x * 16384 + e;
        for (int bb = 0; bb < 32; bb++) {
            float s = 0.f;
            #pragma unroll
            for (int k = 0; k < 16; k++) s += wcol[k] * h2s[bb][k];
            po[bb * 512] = s;
        }
    }
}

// ---------------------------------------------------------------------------
// Attention: reduce pa -> a[b,:]; scores = v.tanh(enc_proj + a); softmax; ctx.
// 32 blocks (one per batch) x 256 threads.
// ---------------------------------------------------------------------------
__global__ __launch_bounds__(256)
void attn_step(const float* __restrict__ pa, const float* __restrict__ enc_pj,
               const bf16* __restrict__ enc, const float* __restrict__ v_w,
               bf16* __restrict__ ctx)
{
    __shared__ __attribute__((aligned(16))) float a_s[512];
    __shared__ __attribute__((aligned(16))) float vw_s[512];
    __shared__ float sc[64];
    __shared__ float wsm[64];
    const int b = blockIdx.x, tid = threadIdx.x;

    vw_s[tid] = v_w[tid];
    vw_s[256 + tid] = v_w[256 + tid];

    float sx = 0.f, sy = 0.f;
    const float* pb = pa + b * 512 + tid * 2;
    #pragma unroll 8
    for (int w = 0; w < 64; w++) {
        float2 v = *reinterpret_cast<const float2*>(pb + (size_t)w * 16384);
        sx += v.x; sy += v.y;
    }
    a_s[2 * tid] = sx; a_s[2 * tid + 1] = sy;
    __syncthreads();

    const int sI = tid >> 2, q = tid & 3;
    const float4* ep4 = reinterpret_cast<const float4*>(enc_pj + ((size_t)b * 64 + sI) * 512 + q * 128);
    const float4* as4 = reinterpret_cast<const float4*>(a_s + q * 128);
    const float4* vw4 = reinterpret_cast<const float4*>(vw_s + q * 128);
    float part = 0.f;
    #pragma unroll 4
    for (int e = 0; e < 32; e++) {
        float4 x = ep4[e], a = as4[e], v = vw4[e];
        part += v.x * tanh_fast(x.x + a.x);
        part += v.y * tanh_fast(x.y + a.y);
        part += v.z * tanh_fast(x.z + a.z);
        part += v.w * tanh_fast(x.w + a.w);
    }
    part += __shfl_xor(part, 1);
    part += __shfl_xor(part, 2);
    if (q == 0) sc[sI] = part;
    __syncthreads();

    if (tid < 64) {
        float v = sc[tid];
        float m = v;
        #pragma unroll
        for (int off = 32; off; off >>= 1) m = fmaxf(m, __shfl_xor(m, off));
        float e = __expf(v - m);
        float su = e;
        #pragma unroll
        for (int off = 32; off; off >>= 1) su += __shfl_xor(su, off);
        wsm[tid] = e / su;
    }
    __syncthreads();

    float c0 = 0, c1 = 0, c2 = 0, c3 = 0;
    const bf16* eb = enc + (size_t)b * 65536 + tid * 4;
    for (int s = 0; s < 64; s++) {
        float w = wsm[s];
        ushort4 u = *reinterpret_cast<const ushort4*>(eb + s * 1024);
        c0 += w * us2f(u.x); c1 += w * us2f(u.y);
        c2 += w * us2f(u.z); c3 += w * us2f(u.w);
    }
    ushort4 o;
    bf16 t0 = __float2bfloat16(c0), t1 = __float2bfloat16(c1);
    bf16 t2 = __float2bfloat16(c2), t3 = __float2bfloat16(c3);
    o.x = *(unsigned short*)&t0; o.y = *(unsigned short*)&t1;
    o.z = *(unsigned short*)&t2; o.w = *(unsigned short*)&t3;
    *reinterpret_cast<ushort4*>(ctx + b * 1024 + tid * 4) = o;
}

// ---------------------------------------------------------------------------
__global__ void init_k(float* __restrict__ h_f, bf16* __restrict__ h_bf,
                       bf16* __restrict__ hall_pad, int* __restrict__ idx_dec,
                       const int* __restrict__ tgt)
{
    const int i = blockIdx.x * blockDim.x + threadIdx.x;
    if (i < 32768) {
        h_f[i] = 0.f;
        h_bf[i] = __float2bfloat16(0.f);
        hall_pad[i] = __float2bfloat16(0.f);
    }
    if (i < 2048) {
        int v = 0;
        if (i < 2016) { int bb = i / 63; int tq = i - bb * 63; v = tgt[bb * 64 + tq]; }
        idx_dec[i] = v;
    }
}

// ---------------------------------------------------------------------------
extern "C" void kernel_launch(void* const* d_in, const int* in_sizes, int n_in,
                              void* d_out, int out_size, void* d_ws, size_t ws_size,
                              hipStream_t stream)
{
    const int*   src       = (const int*)d_in[0];
    const int*   tgt       = (const int*)d_in[1];
    const float* src_embed = (const float*)d_in[2];
    const float* tgt_embed = (const float*)d_in[3];
    const float* enc_Wih   = (const float*)d_in[4];
    const float* enc_Whh   = (const float*)d_in[5];
    const float* enc_bih   = (const float*)d_in[6];
    const float* enc_bhh   = (const float*)d_in[7];
    const float* dec_Wih   = (const float*)d_in[8];
    const float* dec_Whh   = (const float*)d_in[9];
    const float* dec_bih   = (const float*)d_in[10];
    const float* dec_bhh   = (const float*)d_in[11];
    const float* attn_W    = (const float*)d_in[12];
    const float* attn_b    = (const float*)d_in[13];
    const float* v_w       = (const float*)d_in[14];
    const float* fc_W      = (const float*)d_in[15];
    const float* fc_b      = (const float*)d_in[16];

    char* w = (char*)d_ws;
    float* X_enc      = (float*)(w);                 // [2048][3072] f32
    float* X_dec      = (float*)(w + 25165824);      // [2048][3072] f32
    bf16*  enc_bf     = (bf16*) (w + 50331648);      // [32][64][1024] bf16
    float* enc_pj     = (float*)(w + 54525952);      // [2048][512] f32
    bf16*  H_all      = (bf16*) (w + 58720256);      // [2048][1024] bf16
    float* h_f        = (float*)(w + 62914560);      // 2 x [32][1024] f32
    bf16*  h_bf       = (bf16*) (w + 63176704);      // 2 x [32][1024] bf16
    bf16*  ctx_bf     = (bf16*) (w + 63307776);      // [32][1024] bf16
    float* pa         = (float*)(w + 63373312);      // [64][32][512] f32
    int*   idx_dec    = (int*)  (w + 67567616);      // [2048]
    bf16*  enc_Whh_bf = (bf16*) (w + 67575808);      // [3072][1024] bf16
    bf16*  dec_Whh_bf = (bf16*) (w + 73867264);      // [3072][1024] bf16
    bf16*  dec_Wih_bf = (bf16*) (w + 80158720);      // [3072][1536] bf16
    // total: 89,595,904 bytes

    init_k<<<128, 256, 0, stream>>>(h_f, h_bf, H_all + 2016 * 1024, idx_dec, tgt);
    cvt_f32_bf16<<<3072, 256, 0, stream>>>(enc_Whh, enc_Whh_bf, 3145728);
    cvt_f32_bf16<<<3072, 256, 0, stream>>>(dec_Whh, dec_Whh_bf, 3145728);
    cvt_f32_bf16<<<4608, 256, 0, stream>>>(dec_Wih, dec_Wih_bf, 4718592);

    // X_enc = gather(src_embed, src) @ enc_Wih^T + enc_bih
    gemm_bt<float, float, true, false><<<dim3(24, 16), 256, 0, stream>>>(
        src_embed, src, 512, enc_Wih, 512, 0, enc_bih, X_enc, 3072, 2048, 512);
    // X_dec = gather(tgt_embed, tgt[:, :-1]) @ dec_Wih[:, :512]^T + dec_bih
    gemm_bt<float, float, true, false><<<dim3(24, 16), 256, 0, stream>>>(
        tgt_embed, idx_dec, 512, dec_Wih, 1536, 0, dec_bih, X_dec, 3072, 2048, 512);

    for (int t = 0; t < 64; t++) {
        int cur = t & 1, nxt = cur ^ 1;
        enc_step<<<64, 512, 0, stream>>>(h_bf + cur * 32768, h_f + cur * 32768, X_enc, t,
                                         enc_Whh_bf, enc_bhh,
                                         h_f + nxt * 32768, h_bf + nxt * 32768, enc_bf,
                                         attn_W, pa, (t == 63) ? 1 : 0);
    }

    // enc_proj = enc @ We^T + attn_b   (We = attn_W[:, 1024:])
    gemm_bt<bf16, float, false, false><<<dim3(4, 16), 256, 0, stream>>>(
        enc_bf, nullptr, 1024, attn_W, 2048, 1024, attn_b, enc_pj, 512, 2048, 1024);

    for (int t = 0; t < 63; t++) {
        int cur = t & 1, nxt = cur ^ 1;
        attn_step<<<32, 256, 0, stream>>>(pa, enc_pj, enc_bf, v_w, ctx_bf);
        dec_step<<<64, 512, 0, stream>>>(h_bf + cur * 32768, h_f + cur * 32768, ctx_bf,
                                         X_dec, t, dec_Whh_bf, dec_bhh, dec_Wih_bf,
                                         h_f + nxt * 32768, h_bf + nxt * 32768, H_all,
                                         attn_W, pa, (t < 62) ? 1 : 0);
    }

    // logits = H_all @ fc_W^T + fc_b  -> d_out (f32), rows m = b*63+t
    // SWAP grid: M-tiles x-fastest so each fc_W panel's 16 consumers co-run.
    gemm_bt<bf16, float, false, true><<<dim3(16, 250), 256, 0, stream>>>(
        H_all, nullptr, 1024, fc_W, 1024, 0, fc_b, (float*)d_out, 32000, 2016, 1024);
}